// Round 6
// baseline (254.420 us; speedup 1.0000x reference)
//
#include <hip/hip_runtime.h>

// SlotAttention on MI355X (gfx950).
// R5: gemm_kv restructured for 2 blocks/CU (cross-block MFMA∥LDS overlap,
// m97/m114 mechanism): 256x128 tile, 4 waves, per-wave 128x64, BK=32,
// 2-slot LDS double-buffer (48 KiB), one __syncthreads per K-tile, staging
// issued at body top into the opposite slot. 64B-row LDS, 2-way-max swizzle.

#define TS 64
#define TD 4096
#define BATCH 8
#define HC 1024
#define NHEAD 16
#define MD (TD*BATCH)   // 32768
#define MS (TS*BATCH)   // 512
#define NCHUNK 8
#define CHTOK (TD/NCHUNK) // 512

typedef __attribute__((ext_vector_type(8))) __bf16 bf16x8;
typedef __attribute__((ext_vector_type(4))) float f32x4;
typedef __attribute__((ext_vector_type(4))) unsigned short u16x4;
typedef __attribute__((ext_vector_type(8))) unsigned short u16x8;

__device__ __forceinline__ unsigned short f2bf(float x){
  union { float f; unsigned u; } v; v.f = x;
  unsigned r = v.u + 0x7FFFu + ((v.u >> 16) & 1u);
  return (unsigned short)(r >> 16);
}

__device__ __forceinline__ void gll16(const void* g, void* l){
  __builtin_amdgcn_global_load_lds((__attribute__((address_space(1))) void*)g,
                                   (__attribute__((address_space(3))) void*)l, 16, 0, 0);
}

// Fused f32->bf16 convert for all five inputs (one launch).
// f32x4 units: d 8388608 | s 131072 | Wq 262144 | Wk 262144 | Wv 262144.
__global__ void cvt_all(const float* __restrict__ d, const float* __restrict__ s,
                        const float* __restrict__ wq, const float* __restrict__ wk,
                        const float* __restrict__ wv,
                        unsigned short* __restrict__ dbf, unsigned short* __restrict__ sbf,
                        unsigned short* __restrict__ wqb, unsigned short* __restrict__ wkb,
                        unsigned short* __restrict__ wvb){
  long i = (long)blockIdx.x * 256 + threadIdx.x;
  const float* src; unsigned short* dst; long off;
  if (i < 8388608L)      { src = d;  dst = dbf; off = i; }
  else if (i < 8519680L) { src = s;  dst = sbf; off = i - 8388608L; }
  else if (i < 8781824L) { src = wq; dst = wqb; off = i - 8519680L; }
  else if (i < 9043968L) { src = wk; dst = wkb; off = i - 8781824L; }
  else                   { src = wv; dst = wvb; off = i - 9043968L; }
  f32x4 f = ((const f32x4*)src)[off];
  u16x4 o;
  o[0] = f2bf(f[0]); o[1] = f2bf(f[1]); o[2] = f2bf(f[2]); o[3] = f2bf(f[3]);
  ((u16x4*)dst)[off] = o;
}

// ---------------------------------------------------------------------------
// Fused K|V GEMM: C[32768 x 2048] = A @ [Wk;Wv]^T + [bk;bv], bf16 in/out.
// Tile 256x128 (M x N), 4 waves (2M x 2N), per-wave 128x64 output.
// BK=32: LDS slot = A 16KB + B 8KB; 2 slots = 48KB -> 2 blocks/CU (VGPR<256).
// Per K-tile: stage(t+1) -> opposite slot (6 gll16/wave, issued first),
// 12 ds_read_b128 + 32 MFMA, one __syncthreads (vmcnt0+lgkm0+barrier).
// Overlap comes from the co-resident block running antiphase (m97/m114).
// LDS rows are 64B (4 x 16B chunks); chunk XOR (row>>1)&3 -> max 2-way
// aliasing on ds_read_b128 (free, m136). Staging pre-swizzles the global
// source; gll16 dest stays linear (both-sides-or-neither rule).
// ---------------------------------------------------------------------------
__global__ __launch_bounds__(256, 2) void gemm_kv(
    const unsigned short* __restrict__ A,     // [32768][1024]
    const unsigned short* __restrict__ W,     // [2048][1024] = Wk rows then Wv rows
    const float* __restrict__ bk,
    const float* __restrict__ bv,
    unsigned short* __restrict__ Kout,
    unsigned short* __restrict__ Vout)
{
  __shared__ unsigned short As[2][256*32];   // 16 KB per slot
  __shared__ unsigned short Bs[2][128*32];   //  8 KB per slot

  const int nwg = gridDim.x;                 // 2048 (multiple of 8)
  const int cpx = nwg >> 3;
  const int orig = blockIdx.x;
  const int wg = (orig & 7) * cpx + (orig >> 3);   // bijective XCD swizzle
  const int mt = wg >> 4, nt = wg & 15;      // 128 x 16 tiles
  const int tid = threadIdx.x;
  const int lane = tid & 63, w = tid >> 6;   // 4 waves
  const int l15 = lane & 15, lg = lane >> 4;
  const int wm = w >> 1, wn = w & 1;

  // ---- staging addressing: per gll16, wave covers 16 rows x 64B.
  // src chunk pre-swizzled by (lane>>3)&3 (== (localrow>>1)&3).
  const int srow = lane >> 2;                               // 0..15
  const unsigned schunk = (unsigned)(((lane & 3) ^ ((lane >> 3) & 3)) << 4);
  const char* aS = (const char*)A + (size_t)(mt*256) * 2048 + schunk;
  const char* bS = (const char*)W + (size_t)(nt*128) * 2048 + schunk;
  const unsigned ar0 = (unsigned)((  0 + w*16 + srow) * 2048);
  const unsigned ar1 = (unsigned)(( 64 + w*16 + srow) * 2048);
  const unsigned ar2 = (unsigned)((128 + w*16 + srow) * 2048);
  const unsigned ar3 = (unsigned)((192 + w*16 + srow) * 2048);
  const unsigned br0 = ar0, br1 = ar1;
  const unsigned da0 = (unsigned)((  0 + w*16) * 64);       // wave-uniform dests
  const unsigned da1 = (unsigned)(( 64 + w*16) * 64);
  const unsigned da2 = (unsigned)((128 + w*16) * 64);
  const unsigned da3 = (unsigned)((192 + w*16) * 64);

  #define STAGE(t_, buf_) { \
    const size_t ko = (size_t)(t_) * 64; \
    char* dA = (char*)&As[buf_][0]; char* dB = (char*)&Bs[buf_][0]; \
    gll16(aS + ar0 + ko, dA + da0); \
    gll16(aS + ar1 + ko, dA + da1); \
    gll16(aS + ar2 + ko, dA + da2); \
    gll16(aS + ar3 + ko, dA + da3); \
    gll16(bS + br0 + ko, dB + da0); \
    gll16(bS + br1 + ko, dB + da1); \
    __builtin_amdgcn_sched_barrier(0); }

  // ---- fragment read offsets: addr = row*64 + ((lg ^ ((l15>>1)&3))<<4)
  const unsigned ksel = (unsigned)((lg ^ ((l15 >> 1) & 3)) << 4);
  const unsigned aoff = (unsigned)(wm*128 + l15) * 64 + ksel;   // + m*1024
  const unsigned boff = (unsigned)(wn*64  + l15) * 64 + ksel;   // + n*1024

  const f32x4 fz = {0.f, 0.f, 0.f, 0.f};
  f32x4 acc[8][4];
  #pragma unroll
  for (int m = 0; m < 8; ++m)
    #pragma unroll
    for (int n = 0; n < 4; ++n) acc[m][n] = fz;

  #define TILE(buf_) { \
    const char* as_ = (const char*)&As[buf_][0]; \
    const char* bs_ = (const char*)&Bs[buf_][0]; \
    bf16x8 af[8], bf[4]; \
    _Pragma("unroll") \
    for (int m = 0; m < 8; ++m) af[m] = *(const bf16x8*)(as_ + aoff + m*1024u); \
    _Pragma("unroll") \
    for (int n = 0; n < 4; ++n) bf[n] = *(const bf16x8*)(bs_ + boff + n*1024u); \
    __builtin_amdgcn_s_setprio(1); \
    _Pragma("unroll") \
    for (int m = 0; m < 8; ++m) \
      _Pragma("unroll") \
      for (int n = 0; n < 4; ++n) \
        acc[m][n] = __builtin_amdgcn_mfma_f32_16x16x32_bf16(af[m], bf[n], acc[m][n], 0, 0, 0); \
    __builtin_amdgcn_s_setprio(0); }

  // ---- prologue
  STAGE(0, 0)
  __syncthreads();

  // ---- main loop: 32 K-tiles, 2 per iteration (static buffer indices)
  #pragma unroll 1
  for (int tp = 0; tp < 16; ++tp){
    STAGE(2*tp + 1, 1)         // next tile -> slot 1 (its reads done last iter)
    TILE(0)                    // compute tile 2tp from slot 0
    __syncthreads();           // vmcnt(0): slot1 staged; barrier: all waves
    if (tp < 15) STAGE(2*tp + 2, 0)
    TILE(1)
    __syncthreads();
  }

  // ---- epilogue: bias + bf16 store (block's 128 cols uniformly K or V)
  const int ccol = (nt & 7)*128 + wn*64;
  unsigned short* Cb = (nt < 8) ? Kout : Vout;
  const float* bias = (nt < 8) ? bk : bv;
  float bvv[4];
  #pragma unroll
  for (int nf = 0; nf < 4; ++nf) bvv[nf] = bias[ccol + nf*16 + l15];
  #pragma unroll
  for (int mf = 0; mf < 8; ++mf){
    #pragma unroll
    for (int r = 0; r < 4; ++r){
      size_t row = (size_t)(mt*256 + wm*128 + mf*16 + lg*4 + r);
      unsigned short* cp = Cb + row*1024 + ccol;
      #pragma unroll
      for (int nf = 0; nf < 4; ++nf)
        cp[nf*16 + l15] = f2bf(acc[mf][nf][r] + bvv[nf]);
    }
  }
  #undef STAGE
  #undef TILE
}

// ---------------------------------------------------------------------------
// 128^2 GEMM kept for Q (M=512): verified in R0.
// ---------------------------------------------------------------------------
__global__ __launch_bounds__(256) void gemm128(
    const unsigned short* __restrict__ A,
    const unsigned short* __restrict__ W,
    const float* __restrict__ bias,
    unsigned short* __restrict__ C)
{
  __shared__ unsigned short As[128*64];
  __shared__ unsigned short Bs[128*64];
  const int nwg = gridDim.x;
  const int cpx = nwg >> 3;
  const int orig = blockIdx.x;
  const int wg = (orig & 7) * cpx + (orig >> 3);
  const int mt = wg >> 3, nt = wg & 7;
  const int tid = threadIdx.x;
  const int lane = tid & 63, w = tid >> 6;
  const int l15 = lane & 15, lg = lane >> 4;
  const int wr = w >> 1, wc = w & 1;

  const int lrow = lane >> 3;
  const int lch  = (lane & 7) << 4;
  const char* pA[4]; const char* pB[4]; unsigned ldsoff[4];
  #pragma unroll
  for (int j = 0; j < 4; ++j){
    int row = w*32 + j*8 + lrow;
    int sw  = lch ^ ((row & 7) << 4);
    pA[j] = (const char*)A + (size_t)(mt*128 + row) * 2048 + sw;
    pB[j] = (const char*)W + (size_t)(nt*128 + row) * 2048 + sw;
    ldsoff[j] = (unsigned)(w*32 + j*8) * 128;
  }

  const f32x4 fz = {0.f, 0.f, 0.f, 0.f};
  f32x4 acc[4][4];
  #pragma unroll
  for (int m = 0; m < 4; ++m)
    #pragma unroll
    for (int n = 0; n < 4; ++n) acc[m][n] = fz;

  for (int kt = 0; kt < 16; ++kt){
    __syncthreads();
    #pragma unroll
    for (int j = 0; j < 4; ++j){
      gll16(pA[j] + (size_t)kt*128, (char*)As + ldsoff[j]);
      gll16(pB[j] + (size_t)kt*128, (char*)Bs + ldsoff[j]);
    }
    __syncthreads();
    #pragma unroll
    for (int kk = 0; kk < 2; ++kk){
      bf16x8 af[4], bfr[4];
      #pragma unroll
      for (int m = 0; m < 4; ++m){
        int row = wr*64 + m*16 + l15;
        af[m] = *(const bf16x8*)((const char*)As + row*128 + ((lg*16 + kk*64) ^ ((row & 7) << 4)));
      }
      #pragma unroll
      for (int n = 0; n < 4; ++n){
        int row = wc*64 + n*16 + l15;
        bfr[n] = *(const bf16x8*)((const char*)Bs + row*128 + ((lg*16 + kk*64) ^ ((row & 7) << 4)));
      }
      #pragma unroll
      for (int m = 0; m < 4; ++m)
        #pragma unroll
        for (int n = 0; n < 4; ++n)
          acc[m][n] = __builtin_amdgcn_mfma_f32_16x16x32_bf16(af[m], bfr[n], acc[m][n], 0, 0, 0);
    }
  }

  const int ccol0 = nt*128 + wc*64;
  float bv[4];
  #pragma unroll
  for (int n = 0; n < 4; ++n) bv[n] = bias[ccol0 + n*16 + l15];
  #pragma unroll
  for (int m = 0; m < 4; ++m){
    #pragma unroll
    for (int r = 0; r < 4; ++r){
      size_t row = (size_t)(mt*128 + wr*64 + m*16 + lg*4 + r);
      unsigned short* cp = C + row*1024 + ccol0;
      #pragma unroll
      for (int n = 0; n < 4; ++n)
        cp[n*16 + l15] = f2bf(acc[m][n][r] + bv[n]);
    }
  }
}

// one block per (b*16+h, chunk). 256 threads = 4 waves; wave w owns slots [16w,16w+16).
__global__ __launch_bounds__(256) void attn_kernel(
    const unsigned short* __restrict__ Q,
    const unsigned short* __restrict__ K,
    const unsigned short* __restrict__ V,
    float* __restrict__ P)
{
  __shared__ unsigned short Qs[64*64];
  __shared__ unsigned short Ks[64*64];
  __shared__ unsigned short Vt[80*64];
  __shared__ unsigned short Al[64*64];
  __shared__ float red[256];

  const int bh = blockIdx.x;
  const int chunk = blockIdx.y;
  const int bb = bh >> 4, h = bh & 15;
  const int tid = threadIdx.x;
  const int lane = tid & 63, w = tid >> 6;
  const int l15 = lane & 15, lg = lane >> 4;
  const int lrow = lane >> 3, lch = (lane & 7) << 4;

  for (int i = tid; i < 16*64; i += 256){
    int r = i >> 6;
    Vt[(64 + r)*64 + (i & 63)] = (r == 0) ? (unsigned short)0x3F80 : (unsigned short)0;
  }

  #pragma unroll
  for (int j = 0; j < 2; ++j){
    int row = w*16 + j*8 + lrow;
    int sw = lch ^ ((row & 7) << 4);
    const char* g = (const char*)Q + (size_t)(row*BATCH + bb)*2048 + h*128 + sw;
    gll16(g, (char*)Qs + (w*16 + j*8)*128);
  }

  const f32x4 fz = {0.f, 0.f, 0.f, 0.f};
  f32x4 acc[5];
  #pragma unroll
  for (int nb = 0; nb < 5; ++nb) acc[nb] = fz;

  const int vtok = tid >> 2;
  const int vcg  = tid & 3;
  const int t0 = chunk * CHTOK;

  for (int tt = 0; tt < CHTOK/64; ++tt){
    const int tb = t0 + tt*64;
    #pragma unroll
    for (int j = 0; j < 2; ++j){
      int row = w*16 + j*8 + lrow;
      int sw = lch ^ ((row & 7) << 4);
      const char* g = (const char*)K + (size_t)((size_t)(tb + row)*BATCH + bb)*2048 + h*128 + sw;
      gll16(g, (char*)Ks + (w*16 + j*8)*128);
    }
    const char* vg = (const char*)V + (size_t)((size_t)(tb + vtok)*BATCH + bb)*2048 + h*128 + vcg*32;
    u16x8 v0 = *(const u16x8*)vg;
    u16x8 v1 = *(const u16x8*)(vg + 16);
    __syncthreads();

    bf16x8 qa[2];
    #pragma unroll
    for (int kk = 0; kk < 2; ++kk){
      int row = w*16 + l15;
      qa[kk] = *(const bf16x8*)((const char*)Qs + row*128 + ((lg*16 + kk*64) ^ ((row & 7) << 4)));
    }
    float e[4][4];
    #pragma unroll
    for (int nb = 0; nb < 4; ++nb){
      f32x4 s = fz;
      #pragma unroll
      for (int kk = 0; kk < 2; ++kk){
        int row = nb*16 + l15;
        bf16x8 kb = *(const bf16x8*)((const char*)Ks + row*128 + ((lg*16 + kk*64) ^ ((row & 7) << 4)));
        s = __builtin_amdgcn_mfma_f32_16x16x32_bf16(qa[kk], kb, s, 0, 0, 0);
      }
      #pragma unroll
      for (int r = 0; r < 4; ++r) e[nb][r] = __expf(s[r] * 0.125f);
    }
    #pragma unroll
    for (int nb = 0; nb < 4; ++nb){
      float cp = e[nb][0] + e[nb][1] + e[nb][2] + e[nb][3];
      cp += __shfl_xor(cp, 16);
      cp += __shfl_xor(cp, 32);
      if (lg == 0) red[w*64 + nb*16 + l15] = cp;
    }
    __syncthreads();

    #pragma unroll
    for (int nb = 0; nb < 4; ++nb){
      int col = nb*16 + l15;
      float dn = red[col] + red[64 + col] + red[128 + col] + red[192 + col];
      float inv = 1.0f / dn;
      #pragma unroll
      for (int r = 0; r < 4; ++r){
        int row = w*16 + lg*4 + r;
        Al[row*64 + ((((2*col)) ^ ((row & 7) << 4)) >> 1)] = f2bf(e[nb][r] * inv);
      }
    }
    #pragma unroll
    for (int ee = 0; ee < 8; ++ee){
      int c0 = vcg*16 + ee;
      int sw0 = (((c0 & 7) ^ (c0 >> 3)) & 7) << 4;
      Vt[c0*64 + (((2*vtok) ^ sw0) >> 1)] = v0[ee];
    }
    #pragma unroll
    for (int ee = 0; ee < 8; ++ee){
      int c1 = vcg*16 + 8 + ee;
      int sw1 = (((c1 & 7) ^ (c1 >> 3)) & 7) << 4;
      Vt[c1*64 + (((2*vtok) ^ sw1) >> 1)] = v1[ee];
    }
    __syncthreads();

    bf16x8 aa[2];
    #pragma unroll
    for (int kk = 0; kk < 2; ++kk){
      int row = w*16 + l15;
      aa[kk] = *(const bf16x8*)((const char*)Al + row*128 + ((lg*16 + kk*64) ^ ((row & 7) << 4)));
    }
    #pragma unroll
    for (int nb = 0; nb < 5; ++nb){
      #pragma unroll
      for (int kk = 0; kk < 2; ++kk){
        int row = nb*16 + l15;
        int sw = (((row & 7) ^ (row >> 3)) & 7) << 4;
        bf16x8 vb = *(const bf16x8*)((const char*)Vt + row*128 + ((lg*16 + kk*64) ^ sw));
        acc[nb] = __builtin_amdgcn_mfma_f32_16x16x32_bf16(aa[kk], vb, acc[nb], 0, 0, 0);
      }
    }
  }

  float* Pb = P + (size_t)(bh*NCHUNK + chunk) * 64 * 80;
  #pragma unroll
  for (int nb = 0; nb < 5; ++nb){
    #pragma unroll
    for (int r = 0; r < 4; ++r){
      int s = w*16 + lg*4 + r;
      Pb[(size_t)s*80 + nb*16 + l15] = acc[nb][r];
    }
  }
}

__global__ void reduce_out(const float* __restrict__ P, float* __restrict__ out){
  int flat = blockIdx.x * 256 + threadIdx.x;
  int c = flat & 63, s = (flat >> 6) & 63, bh = flat >> 12;
  int bb = bh >> 4, h = bh & 15;
  float sc = 0.f, sn = 0.f;
  #pragma unroll
  for (int ch = 0; ch < NCHUNK; ++ch){
    const float* base = P + ((size_t)(bh*NCHUNK + ch)*64 + s)*80;
    sc += base[c];
    sn += base[64];
  }
  out[((size_t)s*BATCH + bb)*1024 + h*64 + c] = sc / (sn + 0.001f);
}

extern "C" void kernel_launch(void* const* d_in, const int* in_sizes, int n_in,
                              void* d_out, int out_size, void* d_ws, size_t ws_size,
                              hipStream_t stream)
{
  const float* s  = (const float*)d_in[0];
  const float* d  = (const float*)d_in[1];
  const float* Wq = (const float*)d_in[2];
  const float* bq = (const float*)d_in[3];
  const float* Wk = (const float*)d_in[4];
  const float* bk = (const float*)d_in[5];
  const float* Wv = (const float*)d_in[6];
  const float* bv = (const float*)d_in[7];
  float* out = (float*)d_out;

  char* ws = (char*)d_ws;
  unsigned short* dbf = (unsigned short*)(ws);               // 67,108,864
  unsigned short* sbf = (unsigned short*)(ws + 67108864);    //  1,048,576
  unsigned short* wqb = (unsigned short*)(ws + 68157440);    //  2,097,152
  unsigned short* wkb = (unsigned short*)(ws + 70254592);    //  2,097,152 (Wk rows 0..1023)
  unsigned short* wvb = (unsigned short*)(ws + 72351744);    //  2,097,152 (Wv rows = wkb rows 1024..2047)
  unsigned short* Qw  = (unsigned short*)(ws + 74448896);    //  1,048,576
  unsigned short* Kw  = (unsigned short*)(ws + 75497472);    // 67,108,864
  unsigned short* Vw  = (unsigned short*)(ws + 142606336);   // 67,108,864
  float*          Pw  = (float*)(ws + 209715200);            // 20,971,520

  (void)in_sizes; (void)n_in; (void)out_size; (void)ws_size;

  cvt_all<<<36352, 256, 0, stream>>>(d, s, Wq, Wk, Wv, dbf, sbf, wqb, wkb, wvb);

  gemm128<<<(MS/128)*8, 256, 0, stream>>>(sbf, wqb, bq, Qw);
  gemm_kv<<<(MD/256)*16, 256, 0, stream>>>(dbf, wkb, bk, bv, Kw, Vw);

  attn_kernel<<<dim3(128, NCHUNK), 256, 0, stream>>>(Qw, Kw, Vw, Pw);

  reduce_out<<<(TS*BATCH*HC)/256, 256, 0, stream>>>(Pw, out);
}